// Round 11
// baseline (566.374 us; speedup 1.0000x reference)
//
#include <hip/hip_runtime.h>
#include <hip/hip_bf16.h>

#define NN 20000      // nodes
#define NE 640000     // edges (= GCN rows)
#define TAILN (NE - NN)
#define F  128
#define EPSN 1e-5f

typedef __bf16 bf16;
typedef bf16  bf16x8 __attribute__((ext_vector_type(8)));
typedef bf16  bf16x4 __attribute__((ext_vector_type(4)));
typedef float f32x4  __attribute__((ext_vector_type(4)));
typedef unsigned short u16;

// ---- K_cvt: sniff int64/int32 edge_index, normalize, count deg + tail src/dst counts ---
__global__ void k_cvt_idx(const void* __restrict__ ei_raw, int* __restrict__ srcb,
                          int* __restrict__ dstb, int* __restrict__ cnt,
                          int* __restrict__ cst, int* __restrict__ cdt) {
  const int* e32 = (const int*)ei_raw;
  const long long* e64 = (const long long*)ei_raw;
  bool is64 = true;
#pragma unroll
  for (int k = 0; k < 8; ++k) is64 = is64 && (e32[2 * k + 1] == 0);
  int e = blockIdx.x * 256 + threadIdx.x;
  if (e < NE) {
    int s, d;
    if (is64) { s = (int)e64[e]; d = (int)e64[NE + e]; }
    else      { s = e32[e];      d = e32[NE + e]; }
    srcb[e] = s; dstb[e] = d;
    atomicAdd(&cnt[d], 1);
    if (e >= NN) { atomicAdd(&cst[s], 1); atomicAdd(&cdt[d], 1); }
  }
}

// ---- K1: xa = x@W1[:128], xb = x@W1[128:]  (fp32 compute, bf16 store) ------------------
__global__ __launch_bounds__(256) void k1_gemm1(const float* __restrict__ x,
        const float* __restrict__ W1, bf16* __restrict__ xa, bf16* __restrict__ xb) {
  __shared__ float XT[64][129];
  int row0 = blockIdx.x * 64;
  int half = blockIdx.y >> 1;         // 0 -> xa, 1 -> xb
  int cb   = (blockIdx.y & 1) * 64;   // column base
  const float* W = W1 + (size_t)half * F * F;
  bf16* out = half ? xb : xa;
  int t = threadIdx.x;
#pragma unroll
  for (int i = 0; i < 8; ++i) {
    int flat = i * 1024 + t * 4;
    int r = flat >> 7, c = flat & 127;
    int gr = row0 + r;
    f32x4 v = {0.f, 0.f, 0.f, 0.f};
    if (gr < NN) v = *(const f32x4*)(x + (size_t)gr * F + c);
    XT[r][c] = v[0]; XT[r][c + 1] = v[1]; XT[r][c + 2] = v[2]; XT[r][c + 3] = v[3];
  }
  __syncthreads();
  int tc = t & 15, tr = t >> 4;
  float acc[4][4] = {};
  for (int k = 0; k < F; ++k) {
    f32x4 wv = *(const f32x4*)(W + (size_t)k * F + cb + tc * 4);
    float x0 = XT[tr * 4 + 0][k], x1 = XT[tr * 4 + 1][k];
    float x2 = XT[tr * 4 + 2][k], x3 = XT[tr * 4 + 3][k];
#pragma unroll
    for (int j = 0; j < 4; ++j) {
      acc[0][j] += x0 * wv[j]; acc[1][j] += x1 * wv[j];
      acc[2][j] += x2 * wv[j]; acc[3][j] += x3 * wv[j];
    }
  }
#pragma unroll
  for (int i = 0; i < 4; ++i) {
    int gr = row0 + tr * 4 + i;
    if (gr < NN) {
      bf16x4 o;
#pragma unroll
      for (int j = 0; j < 4; ++j) o[j] = (bf16)acc[i][j];
      *(bf16x4*)(out + (size_t)gr * F + cb + tc * 4) = o;
    }
  }
}

// ---- K3: exclusive scan (shuffle-based) -> csr ptr, cursor, dinv, invdeg ---------------
__global__ __launch_bounds__(1024) void k3_scan(const int* __restrict__ cnt,
        int* __restrict__ ptr, int* __restrict__ cursor,
        float* __restrict__ dinv, float* __restrict__ invdeg) {
  __shared__ int wsum[16];
  __shared__ int carry_s;
  int t = threadIdx.x;
  int lane = t & 63, wv = t >> 6;
  if (t == 0) carry_s = 0;
  __syncthreads();
  for (int c0 = 0; c0 < NN; c0 += 1024) {
    int i = c0 + t;
    int v = (i < NN) ? cnt[i] : 0;
    int s = v;
#pragma unroll
    for (int off = 1; off < 64; off <<= 1) {
      int n = __shfl_up(s, off);
      if (lane >= off) s += n;
    }
    if (lane == 63) wsum[wv] = s;
    __syncthreads();
    int carry = carry_s;
    int wbase = 0;
#pragma unroll
    for (int k2 = 0; k2 < 16; ++k2) wbase += (k2 < wv) ? wsum[k2] : 0;
    int incl = s + wbase;
    if (i < NN) {
      int excl = carry + incl - v;
      ptr[i] = excl; cursor[i] = excl;
      float deg = (float)(v + 1);
      dinv[i] = rsqrtf(deg);
      invdeg[i] = 1.0f / deg;
    }
    __syncthreads();
    if (t == 1023) carry_s = carry + incl;
    __syncthreads();
  }
  if (t == 0) ptr[NN] = carry_s;
}

// ==== kB: fused [k4hx | k5] — no LDS, low VGPR in both branches =========================
// k4hx: hx[j] = [ dinv[j]*hh_row(j) | xa_row(j) ]  (512B interleaved rows)
__global__ __launch_bounds__(256) void kB_fused(const int* __restrict__ srcb,
        const int* __restrict__ dstb, const bf16* __restrict__ xa,
        const bf16* __restrict__ xb, const float* __restrict__ dinv,
        bf16* __restrict__ hx, int* __restrict__ cursor, int* __restrict__ csr_s) {
  int bid = blockIdx.x;
  int t = threadIdx.x;
  if (bid < 2500) {
    // ---- k4hx: 32 threads/row; ch<16 computes dinv*hh half, ch>=16 copies xa half ----
    int flat = bid * 256 + t;
    int j = flat >> 5, ch = flat & 31;
    if (j >= NN) return;
    if (ch < 16) {
      int s = srcb[j], d = dstb[j];
      float dj = dinv[j];
      bf16x8 a = *(const bf16x8*)(xa + (size_t)s * F + ch * 8);
      bf16x8 b = *(const bf16x8*)(xb + (size_t)d * F + ch * 8);
      bf16x8 o;
#pragma unroll
      for (int m = 0; m < 8; ++m) o[m] = (bf16)(dj * ((float)a[m] + (float)b[m]));
      *(bf16x8*)(hx + (size_t)j * 256 + ch * 8) = o;
    } else {
      int c8 = (ch - 16) * 8;
      bf16x8 a = *(const bf16x8*)(xa + (size_t)j * F + c8);
      *(bf16x8*)(hx + (size_t)j * 256 + 128 + c8) = a;
    }
  } else {
    // ---- k5: CSR fill (bucket by dst, store src | tail-flag<<16) ----
    int e = (bid - 2500) * 256 + t;
    if (e < NE) {
      int d = dstb[e];
      int pos = atomicAdd(&cursor[d], 1);
      csr_s[pos] = srcb[e] | ((e >= NN) ? (1 << 16) : 0);
    }
  }
}

// ---- K6: conv1 head + tail-cross; gathers pre-scaled hd rows (no dinv in loop) ---------
__global__ __launch_bounds__(256) void k6_conv1cross(const int* __restrict__ ptr,
        const int* __restrict__ csr_s, const bf16* __restrict__ hx,
        const bf16* __restrict__ xb,
        const float* __restrict__ dinv,
        const float* __restrict__ b1, float* __restrict__ h1h,
        float* __restrict__ crossrow) {
  int w = threadIdx.x >> 6, lane = threadIdx.x & 63;
  int g = lane >> 4, k = lane & 15;
  int i = blockIdx.x * 4 + w;
  int c0 = k * 8;
  int beg = ptr[i], end = ptr[i + 1];
  float acc[8] = {0,0,0,0,0,0,0,0}, z[8] = {0,0,0,0,0,0,0,0};
  int q = beg + g;
  for (; q + 4 < end; q += 8) {
    int v0 = csr_s[q], v1 = csr_s[q + 4];
    int s0 = v0 & 0xFFFF, s1 = v1 & 0xFFFF;
    float f0 = (v0 >> 16) ? 1.f : 0.f, f1 = (v1 >> 16) ? 1.f : 0.f;
    const bf16* r0 = hx + (size_t)s0 * 256 + c0;
    const bf16* r1 = hx + (size_t)s1 * 256 + c0;
    bf16x8 h0 = *(const bf16x8*)r0;
    bf16x8 x0 = *(const bf16x8*)(r0 + 128);
    bf16x8 h1 = *(const bf16x8*)r1;
    bf16x8 x1 = *(const bf16x8*)(r1 + 128);
#pragma unroll
    for (int j = 0; j < 8; ++j) {
      acc[j] += (float)h0[j] + (float)h1[j];
      z[j]   += f0 * (float)x0[j] + f1 * (float)x1[j];
    }
  }
  if (q < end) {
    int v0 = csr_s[q];
    int s0 = v0 & 0xFFFF;
    float f0 = (v0 >> 16) ? 1.f : 0.f;
    const bf16* r0 = hx + (size_t)s0 * 256 + c0;
    bf16x8 h0 = *(const bf16x8*)r0;
    bf16x8 x0 = *(const bf16x8*)(r0 + 128);
#pragma unroll
    for (int j = 0; j < 8; ++j) {
      acc[j] += (float)h0[j];
      z[j]   += f0 * (float)x0[j];
    }
  }
#pragma unroll
  for (int m = 16; m < 64; m <<= 1) {
#pragma unroll
    for (int j = 0; j < 8; ++j) {
      acc[j] += __shfl_xor(acc[j], m);
      z[j]   += __shfl_xor(z[j], m);
    }
  }
  if (g == 0) {
    float di = dinv[i];
    bf16x8 self = *(const bf16x8*)(hx + (size_t)i * 256 + c0);   // = dinv[i]*hh[i]
    f32x4 bA = *(const f32x4*)(b1 + c0), bB = *(const f32x4*)(b1 + c0 + 4);
    f32x4 o0, o1;
#pragma unroll
    for (int j = 0; j < 4; ++j) {
      o0[j] = di * (acc[j]     + (float)self[j])     + bA[j];
      o1[j] = di * (acc[j + 4] + (float)self[j + 4]) + bB[j];
    }
    *(f32x4*)(h1h + (size_t)i * F + c0) = o0;
    *(f32x4*)(h1h + (size_t)i * F + c0 + 4) = o1;
  } else if (g == 1) {
    bf16x8 xbv = *(const bf16x8*)(xb + (size_t)i * F + c0);
    f32x4 o0, o1;
#pragma unroll
    for (int j = 0; j < 4; ++j) {
      o0[j] = (float)xbv[j]     * z[j];
      o1[j] = (float)xbv[j + 4] * z[j + 4];
    }
    *(f32x4*)(crossrow + (size_t)i * F + c0) = o0;
    *(f32x4*)(crossrow + (size_t)i * F + c0 + 4) = o1;
  }
}

// ---- K7sr: node-space stats reduce -> statsB[5][128] -----------------------------------
__global__ __launch_bounds__(256) void k7sr(const float* __restrict__ h1h,
        const float* __restrict__ crossrow, const bf16* __restrict__ xa,
        const bf16* __restrict__ xb, const int* __restrict__ cst,
        const int* __restrict__ cdt, float* __restrict__ statsB) {
  int t = threadIdx.x;
  int w = t >> 6, lane = t & 63, k = lane & 15;
  int rg = t >> 4;
  int c0 = k * 8;
  int base = blockIdx.x * 200;
  float A1[8] = {0,0,0,0,0,0,0,0}, A2[8] = {0,0,0,0,0,0,0,0};
  float B1[8] = {0,0,0,0,0,0,0,0}, B2[8] = {0,0,0,0,0,0,0,0};
  float Cc[8] = {0,0,0,0,0,0,0,0};
  for (int r = rg; r < 200; r += 16) {
    int n = base + r;
    f32x4 h0 = *(const f32x4*)(h1h + (size_t)n * F + c0);
    f32x4 h1 = *(const f32x4*)(h1h + (size_t)n * F + c0 + 4);
    f32x4 cr0 = *(const f32x4*)(crossrow + (size_t)n * F + c0);
    f32x4 cr1 = *(const f32x4*)(crossrow + (size_t)n * F + c0 + 4);
    bf16x8 av = *(const bf16x8*)(xa + (size_t)n * F + c0);
    bf16x8 bv = *(const bf16x8*)(xb + (size_t)n * F + c0);
    float ca = (float)cst[n], cb = (float)cdt[n];
#pragma unroll
    for (int j = 0; j < 4; ++j) {
      A1[j] += h0[j]; A2[j] += h0[j] * h0[j];
      A1[j + 4] += h1[j]; A2[j + 4] += h1[j] * h1[j];
      Cc[j] += cr0[j]; Cc[j + 4] += cr1[j];
    }
#pragma unroll
    for (int j = 0; j < 8; ++j) {
      float a = (float)av[j], b = (float)bv[j];
      B1[j] += ca * a + cb * b;
      B2[j] += ca * a * a + cb * b * b;
    }
  }
#pragma unroll
  for (int m = 16; m < 64; m <<= 1) {
#pragma unroll
    for (int j = 0; j < 8; ++j) {
      A1[j] += __shfl_xor(A1[j], m); A2[j] += __shfl_xor(A2[j], m);
      B1[j] += __shfl_xor(B1[j], m); B2[j] += __shfl_xor(B2[j], m);
      Cc[j] += __shfl_xor(Cc[j], m);
    }
  }
  __shared__ float L[4][5][128];
  if (lane < 16) {
#pragma unroll
    for (int j = 0; j < 8; ++j) {
      L[w][0][c0 + j] = A1[j]; L[w][1][c0 + j] = A2[j];
      L[w][2][c0 + j] = B1[j]; L[w][3][c0 + j] = B2[j];
      L[w][4][c0 + j] = Cc[j];
    }
  }
  __syncthreads();
  if (t < 128) {
#pragma unroll
    for (int term = 0; term < 5; ++term) {
      float v = L[0][term][t] + L[1][term][t] + L[2][term][t] + L[3][term][t];
      atomicAdd(&statsB[term * 128 + t], v);
    }
  }
}

// ---- K8: finalize BN affine folds + transpose W2 to bf16 + params4 ---------------------
__global__ __launch_bounds__(256) void k8_final(const float* __restrict__ statsB,
        const float* __restrict__ bn_g, const float* __restrict__ bn_b,
        const float* __restrict__ b1, const float* __restrict__ W2,
        const float* __restrict__ b2, const float* __restrict__ lng,
        const float* __restrict__ lnb, const float* __restrict__ W3,
        float* __restrict__ P, float* __restrict__ Qh, float* __restrict__ Qt,
        u16* __restrict__ W2t, f32x4* __restrict__ params4) {
  int t = threadIdx.x;
  if (t < 128) {
    float A1 = statsB[t], A2 = statsB[128 + t], B1v = statsB[256 + t];
    float B2v = statsB[384 + t], Cv = statsB[512 + t];
    float b1c = b1[t];
    float S = A1 + B1v + (float)TAILN * b1c;
    float Q = A2 + B2v + 2.f * Cv + 2.f * b1c * B1v + (float)TAILN * b1c * b1c;
    float mean = S * (1.0f / NE);
    float var = Q * (1.0f / NE) - mean * mean;
    float rs = rsqrtf(var + EPSN);
    float p = bn_g[t] * rs;
    float sh = bn_b[t] - mean * p;
    P[t] = p; Qh[t] = sh; Qt[t] = p * b1c + sh;
    f32x4 pr = {b2[t], lng[t], lnb[t], W3[t]};
    params4[t] = pr;
  }
  for (int i = 0; i < 64; ++i) {
    int flat = i * 256 + t;
    int k = flat >> 7, c = flat & 127;
    union { bf16 b; u16 u; } cv;
    cv.b = (bf16)W2[(size_t)k * F + c];
    W2t[(size_t)c * F + k] = cv.u;   // W2t[c][k]
  }
}

// ---- K9a: head GEMM g2 = dinv[row] * (relu(P*h1h+Qh) @ W2)  (bf16 MFMA) ----------------
__global__ __launch_bounds__(256) void k9a_headgemm(const float* __restrict__ h1h,
        const float* __restrict__ P, const float* __restrict__ Qh,
        const u16* __restrict__ W2t, const float* __restrict__ dinv,
        bf16* __restrict__ g2) {
  __shared__ __align__(16) bf16 A[64 * 128];
  __shared__ __align__(16) bf16 B[128 * 128];
  int t = threadIdx.x;
  int row0 = blockIdx.x * 64;
  const bf16x8* srcB = (const bf16x8*)W2t;
#pragma unroll
  for (int i = 0; i < 8; ++i) {
    int ch = i * 256 + t;
    int r = ch >> 4, cir = ch & 15;
    *(bf16x8*)&B[r * 128 + ((cir ^ (r & 7)) << 3)] = srcB[ch];
  }
  {
    int r = t >> 2, sub = t & 3;
    int gr = row0 + r;
#pragma unroll
    for (int j = 0; j < 4; ++j) {
      int c0 = sub * 32 + j * 8;
      f32x4 v0 = {0.f,0.f,0.f,0.f}, v1 = {0.f,0.f,0.f,0.f};
      if (gr < NN) {
        v0 = *(const f32x4*)(h1h + (size_t)gr * F + c0);
        v1 = *(const f32x4*)(h1h + (size_t)gr * F + c0 + 4);
      }
      f32x4 p0 = *(const f32x4*)(P + c0), p1 = *(const f32x4*)(P + c0 + 4);
      f32x4 q0 = *(const f32x4*)(Qh + c0), q1 = *(const f32x4*)(Qh + c0 + 4);
      bf16x8 o;
#pragma unroll
      for (int m = 0; m < 4; ++m) {
        o[m]     = (bf16)fmaxf(v0[m] * p0[m] + q0[m], 0.f);
        o[m + 4] = (bf16)fmaxf(v1[m] * p1[m] + q1[m], 0.f);
      }
      int ch = c0 >> 3;
      *(bf16x8*)&A[r * 128 + ((ch ^ (r & 7)) << 3)] = o;
    }
  }
  __syncthreads();
  int lane = t & 63, w = t >> 6;
  int lr = lane & 15, g = lane >> 4;
  int arow = w * 16 + lr;
  bf16x8 af[4];
#pragma unroll
  for (int kk = 0; kk < 4; ++kk)
    af[kk] = *(const bf16x8*)&A[arow * 128 + (((kk * 4 + g) ^ (arow & 7)) << 3)];
  f32x4 acc[8];
#pragma unroll
  for (int n = 0; n < 8; ++n) {
    f32x4 a = {0.f,0.f,0.f,0.f};
    int col = n * 16 + lr;
#pragma unroll
    for (int kk = 0; kk < 4; ++kk) {
      bf16x8 bfr = *(const bf16x8*)&B[col * 128 + (((kk * 4 + g) ^ (col & 7)) << 3)];
      a = __builtin_amdgcn_mfma_f32_16x16x32_bf16(af[kk], bfr, a, 0, 0, 0);
    }
    acc[n] = a;
  }
#pragma unroll
  for (int r4 = 0; r4 < 4; ++r4) {
    int gr = row0 + w * 16 + g * 4 + r4;
    if (gr < NN) {
      float dr = dinv[gr];
#pragma unroll
      for (int n = 0; n < 8; ++n)
        g2[(size_t)gr * F + n * 16 + lr] = (bf16)(acc[n][r4] * dr);
    }
  }
}

// ==== kC: fused [k9c | k9b] — VGPR pinned to the 128 tier via launch_bounds =============
__global__ __launch_bounds__(256, 4) void kC_fused(const int* __restrict__ srcb,
        const int* __restrict__ dstb, const bf16* __restrict__ xa,
        const bf16* __restrict__ xb, const float* __restrict__ P,
        const float* __restrict__ Qt, const u16* __restrict__ W2t,
        const f32x4* __restrict__ params4, const float* __restrict__ b3,
        const int* __restrict__ ptr, const int* __restrict__ csr_s,
        const bf16* __restrict__ g2, const float* __restrict__ dinv,
        const float* __restrict__ b2, const float* __restrict__ lng,
        const float* __restrict__ lnb, const float* __restrict__ W3,
        float* __restrict__ out) {
  __shared__ __align__(16) bf16 B[128 * 128];
  int bid = blockIdx.x;
  int t = threadIdx.x;
  int lane = t & 63, w = t >> 6;
  if (bid < 2422) {
    // ---- k9c: tail fused (256 edges/block, LDS B) ----
    const bf16x8* srcB = (const bf16x8*)W2t;
#pragma unroll
    for (int i = 0; i < 8; ++i) {
      int ch = i * 256 + t;
      int r = ch >> 4, cir = ch & 15;
      *(bf16x8*)&B[r * 128 + ((cir ^ (r & 7)) << 3)] = srcB[ch];
    }
    __syncthreads();
    int lr = lane & 15, g = lane >> 4;
    int ebase = NN + bid * 256 + w * 64;
    float b3v = b3[0];
    for (int rc = 0; rc < 4; ++rc) {
      int e = ebase + rc * 16 + lr;
      bool ok = (e < NE);
      int se = 0, de = 0;
      if (ok) { se = srcb[e]; de = dstb[e]; }
      bf16x8 af[4];
#pragma unroll
      for (int kk = 0; kk < 4; ++kk) {
        int c0 = kk * 32 + g * 8;
        bf16x8 o;
        if (ok) {
          bf16x8 av = *(const bf16x8*)(xa + (size_t)se * F + c0);
          bf16x8 bv = *(const bf16x8*)(xb + (size_t)de * F + c0);
          f32x4 p0 = *(const f32x4*)(P + c0), p1 = *(const f32x4*)(P + c0 + 4);
          f32x4 q0 = *(const f32x4*)(Qt + c0), q1 = *(const f32x4*)(Qt + c0 + 4);
#pragma unroll
          for (int m = 0; m < 4; ++m) {
            o[m]     = (bf16)fmaxf(((float)av[m] + (float)bv[m]) * p0[m] + q0[m], 0.f);
            o[m + 4] = (bf16)fmaxf(((float)av[m + 4] + (float)bv[m + 4]) * p1[m] + q1[m], 0.f);
          }
        } else {
#pragma unroll
          for (int m = 0; m < 8; ++m) o[m] = (bf16)0.f;
        }
        af[kk] = o;
      }
      f32x4 acc[8];
#pragma unroll
      for (int n = 0; n < 8; ++n) {
        f32x4 a = {0.f,0.f,0.f,0.f};
        int col = n * 16 + lr;
#pragma unroll
        for (int kk = 0; kk < 4; ++kk) {
          bf16x8 bfr = *(const bf16x8*)&B[col * 128 + (((kk * 4 + g) ^ (col & 7)) << 3)];
          a = __builtin_amdgcn_mfma_f32_16x16x32_bf16(af[kk], bfr, a, 0, 0, 0);
        }
        acc[n] = a;
      }
#pragma unroll
      for (int r4 = 0; r4 < 4; ++r4) {
        float vv[8];
        float s = 0.f, q = 0.f;
#pragma unroll
        for (int n = 0; n < 8; ++n) {
          float v = acc[n][r4] + params4[n * 16 + lr][0];
          vv[n] = v; s += v; q += v * v;
        }
#pragma unroll
        for (int m = 1; m < 16; m <<= 1) { s += __shfl_xor(s, m); q += __shfl_xor(q, m); }
        float mean = s * (1.0f / F);
        float var = q * (1.0f / F) - mean * mean;
        float rs = rsqrtf(var + EPSN);
        float o = 0.f;
#pragma unroll
        for (int n = 0; n < 8; ++n) {
          f32x4 pr = params4[n * 16 + lr];
          o += fmaxf((vv[n] - mean) * rs * pr[1] + pr[2], 0.f) * pr[3];
        }
#pragma unroll
        for (int m = 1; m < 16; m <<= 1) o += __shfl_xor(o, m);
        int eo = ebase + rc * 16 + g * 4 + r4;
        if (lr == 0 && eo < NE) out[eo] = o + b3v;
      }
    }
  } else {
    // ---- k9b: head conv2 + LN + relu + W3 (gathers pre-scaled g2 rows) ----
    int g = lane >> 4, k = lane & 15;
    int i = (bid - 2422) * 4 + w;
    int c0 = k * 8;
    int beg = ptr[i], end = ptr[i + 1];
    float acc[8] = {0,0,0,0,0,0,0,0};
    int q = beg + g;
    for (; q + 4 < end; q += 8) {
      int s0 = csr_s[q] & 0xFFFF, s1 = csr_s[q + 4] & 0xFFFF;
      bf16x8 h0 = *(const bf16x8*)(g2 + (size_t)s0 * F + c0);
      bf16x8 h1 = *(const bf16x8*)(g2 + (size_t)s1 * F + c0);
#pragma unroll
      for (int j = 0; j < 8; ++j)
        acc[j] += (float)h0[j] + (float)h1[j];
    }
    if (q < end) {
      int s0 = csr_s[q] & 0xFFFF;
      bf16x8 h0 = *(const bf16x8*)(g2 + (size_t)s0 * F + c0);
#pragma unroll
      for (int j = 0; j < 8; ++j) acc[j] += (float)h0[j];
    }
#pragma unroll
    for (int m = 16; m < 64; m <<= 1) {
#pragma unroll
      for (int j = 0; j < 8; ++j) acc[j] += __shfl_xor(acc[j], m);
    }
    float di = dinv[i];
    bf16x8 self = *(const bf16x8*)(g2 + (size_t)i * F + c0);   // = dinv[i]*h2ph[i]
    f32x4 b2A = *(const f32x4*)(b2 + c0), b2B = *(const f32x4*)(b2 + c0 + 4);
    float h2[8];
#pragma unroll
    for (int j = 0; j < 4; ++j) {
      h2[j]     = di * (acc[j]     + (float)self[j])     + b2A[j];
      h2[j + 4] = di * (acc[j + 4] + (float)self[j + 4]) + b2B[j];
    }
    float s1v = 0.f, s2v = 0.f;
#pragma unroll
    for (int j = 0; j < 8; ++j) { s1v += h2[j]; s2v += h2[j] * h2[j]; }
#pragma unroll
    for (int m = 1; m < 16; m <<= 1) { s1v += __shfl_xor(s1v, m); s2v += __shfl_xor(s2v, m); }
    float mean = s1v * (1.0f / F);
    float var = s2v * (1.0f / F) - mean * mean;
    float rs = rsqrtf(var + EPSN);
    f32x4 lgA = *(const f32x4*)(lng + c0), lgB = *(const f32x4*)(lng + c0 + 4);
    f32x4 lbA = *(const f32x4*)(lnb + c0), lbB = *(const f32x4*)(lnb + c0 + 4);
    f32x4 w3A = *(const f32x4*)(W3 + c0),  w3B = *(const f32x4*)(W3 + c0 + 4);
    float y = 0.f;
#pragma unroll
    for (int j = 0; j < 4; ++j) {
      y += fmaxf((h2[j]     - mean) * rs * lgA[j] + lbA[j], 0.f) * w3A[j];
      y += fmaxf((h2[j + 4] - mean) * rs * lgB[j] + lbB[j], 0.f) * w3B[j];
    }
#pragma unroll
    for (int m = 1; m < 16; m <<= 1) y += __shfl_xor(y, m);
    if (lane == 0) out[i] = y + b3[0];
  }
}

// ======================================================================================
extern "C" void kernel_launch(void* const* d_in, const int* in_sizes, int n_in,
                              void* d_out, int out_size, void* d_ws, size_t ws_size,
                              hipStream_t stream) {
  const float* x   = (const float*)d_in[0];
  const void*  ei  = d_in[1];
  const float* W1  = (const float*)d_in[2];
  const float* b1  = (const float*)d_in[3];
  const float* bng = (const float*)d_in[4];
  const float* bnb = (const float*)d_in[5];
  const float* W2  = (const float*)d_in[6];
  const float* b2  = (const float*)d_in[7];
  const float* lng = (const float*)d_in[8];
  const float* lnb = (const float*)d_in[9];
  const float* W3  = (const float*)d_in[10];
  const float* b3  = (const float*)d_in[11];
  float* out = (float*)d_out;

  char* ws = (char*)d_ws;
  size_t off = 0;
  auto alloc = [&](size_t bytes) -> char* {
    off = (off + 511) & ~(size_t)511;
    char* p = ws + off;
    off += bytes;
    return p;
  };
  const size_t NFh = (size_t)NN * F * 2;   // bf16 node-row tables
  bf16*  xa     = (bf16*)alloc(NFh);
  bf16*  xb     = (bf16*)alloc(NFh);
  bf16*  hx     = (bf16*)alloc((size_t)NN * 256 * 2);  // interleaved [dinv*hh|xa] rows
  float* h1h    = (float*)alloc((size_t)NN * F * 4);
  float* crossr = (float*)alloc((size_t)NN * F * 4);
  int*   srcb   = (int*)alloc((size_t)NE * 4);
  int*   dstb   = (int*)alloc((size_t)NE * 4);
  int*   csr_s  = (int*)alloc((size_t)NE * 4);
  int*   cnt    = (int*)alloc((size_t)NN * 4);
  int*   cst    = (int*)alloc((size_t)NN * 4);
  int*   cdt    = (int*)alloc((size_t)NN * 4);
  int*   ptrb   = (int*)alloc((size_t)(NN + 1) * 4);
  int*   cursor = (int*)alloc((size_t)NN * 4);
  float* dinv   = (float*)alloc((size_t)NN * 4);
  float* invdeg = (float*)alloc((size_t)NN * 4);
  float* statsB = (float*)alloc(5 * 128 * 4);
  float* Pp     = (float*)alloc(128 * 4);
  float* Qh     = (float*)alloc(128 * 4);
  float* Qt     = (float*)alloc(128 * 4);
  u16*   W2t    = (u16*)alloc((size_t)F * F * 2);
  f32x4* params4= (f32x4*)alloc(128 * 16);
  bf16*  g2     = hx;  // alias: hx dead after k6 (k7sr reads xa/xb/h1h/crossr only)

  hipMemsetAsync(cnt, 0, (size_t)NN * 4, stream);
  hipMemsetAsync(cst, 0, (size_t)NN * 4, stream);
  hipMemsetAsync(cdt, 0, (size_t)NN * 4, stream);
  hipMemsetAsync(statsB, 0, 5 * 128 * 4, stream);

  k_cvt_idx<<<2500, 256, 0, stream>>>(ei, srcb, dstb, cnt, cst, cdt);
  k1_gemm1<<<dim3(313, 4), 256, 0, stream>>>(x, W1, xa, xb);
  k3_scan<<<1, 1024, 0, stream>>>(cnt, ptrb, cursor, dinv, invdeg);
  kB_fused<<<5000, 256, 0, stream>>>(srcb, dstb, xa, xb, dinv, hx, cursor, csr_s);
  k6_conv1cross<<<5000, 256, 0, stream>>>(ptrb, csr_s, hx, xb, dinv, b1, h1h, crossr);
  k7sr<<<100, 256, 0, stream>>>(h1h, crossr, xa, xb, cst, cdt, statsB);
  k8_final<<<1, 256, 0, stream>>>(statsB, bng, bnb, b1, W2, b2, lng, lnb, W3,
                                  Pp, Qh, Qt, W2t, params4);
  k9a_headgemm<<<313, 256, 0, stream>>>(h1h, Pp, Qh, W2t, dinv, g2);
  kC_fused<<<7422, 256, 0, stream>>>(srcb, dstb, xa, xb, Pp, Qt, W2t, params4, b3,
                                     ptrb, csr_s, g2, dinv, b2, lng, lnb, W3, out);
}

// Round 12
// 458.900 us; speedup vs baseline: 1.2342x; 1.2342x over previous
//
#include <hip/hip_runtime.h>
#include <hip/hip_bf16.h>

#define NN 20000      // nodes
#define NE 640000     // edges (= GCN rows)
#define TAILN (NE - NN)
#define F  128
#define EPSN 1e-5f

typedef __bf16 bf16;
typedef bf16  bf16x8 __attribute__((ext_vector_type(8)));
typedef bf16  bf16x4 __attribute__((ext_vector_type(4)));
typedef float f32x4  __attribute__((ext_vector_type(4)));
typedef unsigned short u16;

// ---- K_cvt: sniff int64/int32 edge_index, normalize, count deg + tail src/dst counts ---
__global__ void k_cvt_idx(const void* __restrict__ ei_raw, int* __restrict__ srcb,
                          int* __restrict__ dstb, int* __restrict__ cnt,
                          int* __restrict__ cst, int* __restrict__ cdt) {
  const int* e32 = (const int*)ei_raw;
  const long long* e64 = (const long long*)ei_raw;
  bool is64 = true;
#pragma unroll
  for (int k = 0; k < 8; ++k) is64 = is64 && (e32[2 * k + 1] == 0);
  int e = blockIdx.x * 256 + threadIdx.x;
  if (e < NE) {
    int s, d;
    if (is64) { s = (int)e64[e]; d = (int)e64[NE + e]; }
    else      { s = e32[e];      d = e32[NE + e]; }
    srcb[e] = s; dstb[e] = d;
    atomicAdd(&cnt[d], 1);
    if (e >= NN) { atomicAdd(&cst[s], 1); atomicAdd(&cdt[d], 1); }
  }
}

// ---- K1: xa = x@W1[:128], xb = x@W1[128:]  (fp32 compute, bf16 store) ------------------
__global__ __launch_bounds__(256) void k1_gemm1(const float* __restrict__ x,
        const float* __restrict__ W1, bf16* __restrict__ xa, bf16* __restrict__ xb) {
  __shared__ float XT[64][129];
  int row0 = blockIdx.x * 64;
  int half = blockIdx.y >> 1;         // 0 -> xa, 1 -> xb
  int cb   = (blockIdx.y & 1) * 64;   // column base
  const float* W = W1 + (size_t)half * F * F;
  bf16* out = half ? xb : xa;
  int t = threadIdx.x;
#pragma unroll
  for (int i = 0; i < 8; ++i) {
    int flat = i * 1024 + t * 4;
    int r = flat >> 7, c = flat & 127;
    int gr = row0 + r;
    f32x4 v = {0.f, 0.f, 0.f, 0.f};
    if (gr < NN) v = *(const f32x4*)(x + (size_t)gr * F + c);
    XT[r][c] = v[0]; XT[r][c + 1] = v[1]; XT[r][c + 2] = v[2]; XT[r][c + 3] = v[3];
  }
  __syncthreads();
  int tc = t & 15, tr = t >> 4;
  float acc[4][4] = {};
  for (int k = 0; k < F; ++k) {
    f32x4 wv = *(const f32x4*)(W + (size_t)k * F + cb + tc * 4);
    float x0 = XT[tr * 4 + 0][k], x1 = XT[tr * 4 + 1][k];
    float x2 = XT[tr * 4 + 2][k], x3 = XT[tr * 4 + 3][k];
#pragma unroll
    for (int j = 0; j < 4; ++j) {
      acc[0][j] += x0 * wv[j]; acc[1][j] += x1 * wv[j];
      acc[2][j] += x2 * wv[j]; acc[3][j] += x3 * wv[j];
    }
  }
#pragma unroll
  for (int i = 0; i < 4; ++i) {
    int gr = row0 + tr * 4 + i;
    if (gr < NN) {
      bf16x4 o;
#pragma unroll
      for (int j = 0; j < 4; ++j) o[j] = (bf16)acc[i][j];
      *(bf16x4*)(out + (size_t)gr * F + cb + tc * 4) = o;
    }
  }
}

// ---- K3: exclusive scan (shuffle-based) -> csr ptr, cursor, dinv, invdeg ---------------
__global__ __launch_bounds__(1024) void k3_scan(const int* __restrict__ cnt,
        int* __restrict__ ptr, int* __restrict__ cursor,
        float* __restrict__ dinv, float* __restrict__ invdeg) {
  __shared__ int wsum[16];
  __shared__ int carry_s;
  int t = threadIdx.x;
  int lane = t & 63, wv = t >> 6;
  if (t == 0) carry_s = 0;
  __syncthreads();
  for (int c0 = 0; c0 < NN; c0 += 1024) {
    int i = c0 + t;
    int v = (i < NN) ? cnt[i] : 0;
    int s = v;
#pragma unroll
    for (int off = 1; off < 64; off <<= 1) {
      int n = __shfl_up(s, off);
      if (lane >= off) s += n;
    }
    if (lane == 63) wsum[wv] = s;
    __syncthreads();
    int carry = carry_s;
    int wbase = 0;
#pragma unroll
    for (int k2 = 0; k2 < 16; ++k2) wbase += (k2 < wv) ? wsum[k2] : 0;
    int incl = s + wbase;
    if (i < NN) {
      int excl = carry + incl - v;
      ptr[i] = excl; cursor[i] = excl;
      float deg = (float)(v + 1);
      dinv[i] = rsqrtf(deg);
      invdeg[i] = 1.0f / deg;
    }
    __syncthreads();
    if (t == 1023) carry_s = carry + incl;
    __syncthreads();
  }
  if (t == 0) ptr[NN] = carry_s;
}

// ==== kB: fused [k4hx | k5] — no LDS, low VGPR in both branches =========================
// k4hx: hx[j] = [ dinv[j]*hh_row(j) | xa_row(j) ]  (512B interleaved rows)
__global__ __launch_bounds__(256) void kB_fused(const int* __restrict__ srcb,
        const int* __restrict__ dstb, const bf16* __restrict__ xa,
        const bf16* __restrict__ xb, const float* __restrict__ dinv,
        bf16* __restrict__ hx, int* __restrict__ cursor, int* __restrict__ csr_s) {
  int bid = blockIdx.x;
  int t = threadIdx.x;
  if (bid < 2500) {
    // ---- k4hx: 32 threads/row; ch<16 computes dinv*hh half, ch>=16 copies xa half ----
    int flat = bid * 256 + t;
    int j = flat >> 5, ch = flat & 31;
    if (j >= NN) return;
    if (ch < 16) {
      int s = srcb[j], d = dstb[j];
      float dj = dinv[j];
      bf16x8 a = *(const bf16x8*)(xa + (size_t)s * F + ch * 8);
      bf16x8 b = *(const bf16x8*)(xb + (size_t)d * F + ch * 8);
      bf16x8 o;
#pragma unroll
      for (int m = 0; m < 8; ++m) o[m] = (bf16)(dj * ((float)a[m] + (float)b[m]));
      *(bf16x8*)(hx + (size_t)j * 256 + ch * 8) = o;
    } else {
      int c8 = (ch - 16) * 8;
      bf16x8 a = *(const bf16x8*)(xa + (size_t)j * F + c8);
      *(bf16x8*)(hx + (size_t)j * 256 + 128 + c8) = a;
    }
  } else {
    // ---- k5: CSR fill (bucket by dst, store src | tail-flag<<16) ----
    int e = (bid - 2500) * 256 + t;
    if (e < NE) {
      int d = dstb[e];
      int pos = atomicAdd(&cursor[d], 1);
      csr_s[pos] = srcb[e] | ((e >= NN) ? (1 << 16) : 0);
    }
  }
}

// ---- K6: conv1 head + tail-cross; gathers pre-scaled hd rows (no dinv in loop) ---------
__global__ __launch_bounds__(256) void k6_conv1cross(const int* __restrict__ ptr,
        const int* __restrict__ csr_s, const bf16* __restrict__ hx,
        const bf16* __restrict__ xb,
        const float* __restrict__ dinv,
        const float* __restrict__ b1, float* __restrict__ h1h,
        float* __restrict__ crossrow) {
  int w = threadIdx.x >> 6, lane = threadIdx.x & 63;
  int g = lane >> 4, k = lane & 15;
  int i = blockIdx.x * 4 + w;
  int c0 = k * 8;
  int beg = ptr[i], end = ptr[i + 1];
  float acc[8] = {0,0,0,0,0,0,0,0}, z[8] = {0,0,0,0,0,0,0,0};
  int q = beg + g;
  for (; q + 4 < end; q += 8) {
    int v0 = csr_s[q], v1 = csr_s[q + 4];
    int s0 = v0 & 0xFFFF, s1 = v1 & 0xFFFF;
    float f0 = (v0 >> 16) ? 1.f : 0.f, f1 = (v1 >> 16) ? 1.f : 0.f;
    const bf16* r0 = hx + (size_t)s0 * 256 + c0;
    const bf16* r1 = hx + (size_t)s1 * 256 + c0;
    bf16x8 h0 = *(const bf16x8*)r0;
    bf16x8 x0 = *(const bf16x8*)(r0 + 128);
    bf16x8 h1 = *(const bf16x8*)r1;
    bf16x8 x1 = *(const bf16x8*)(r1 + 128);
#pragma unroll
    for (int j = 0; j < 8; ++j) {
      acc[j] += (float)h0[j] + (float)h1[j];
      z[j]   += f0 * (float)x0[j] + f1 * (float)x1[j];
    }
  }
  if (q < end) {
    int v0 = csr_s[q];
    int s0 = v0 & 0xFFFF;
    float f0 = (v0 >> 16) ? 1.f : 0.f;
    const bf16* r0 = hx + (size_t)s0 * 256 + c0;
    bf16x8 h0 = *(const bf16x8*)r0;
    bf16x8 x0 = *(const bf16x8*)(r0 + 128);
#pragma unroll
    for (int j = 0; j < 8; ++j) {
      acc[j] += (float)h0[j];
      z[j]   += f0 * (float)x0[j];
    }
  }
#pragma unroll
  for (int m = 16; m < 64; m <<= 1) {
#pragma unroll
    for (int j = 0; j < 8; ++j) {
      acc[j] += __shfl_xor(acc[j], m);
      z[j]   += __shfl_xor(z[j], m);
    }
  }
  if (g == 0) {
    float di = dinv[i];
    bf16x8 self = *(const bf16x8*)(hx + (size_t)i * 256 + c0);   // = dinv[i]*hh[i]
    f32x4 bA = *(const f32x4*)(b1 + c0), bB = *(const f32x4*)(b1 + c0 + 4);
    f32x4 o0, o1;
#pragma unroll
    for (int j = 0; j < 4; ++j) {
      o0[j] = di * (acc[j]     + (float)self[j])     + bA[j];
      o1[j] = di * (acc[j + 4] + (float)self[j + 4]) + bB[j];
    }
    *(f32x4*)(h1h + (size_t)i * F + c0) = o0;
    *(f32x4*)(h1h + (size_t)i * F + c0 + 4) = o1;
  } else if (g == 1) {
    bf16x8 xbv = *(const bf16x8*)(xb + (size_t)i * F + c0);
    f32x4 o0, o1;
#pragma unroll
    for (int j = 0; j < 4; ++j) {
      o0[j] = (float)xbv[j]     * z[j];
      o1[j] = (float)xbv[j + 4] * z[j + 4];
    }
    *(f32x4*)(crossrow + (size_t)i * F + c0) = o0;
    *(f32x4*)(crossrow + (size_t)i * F + c0 + 4) = o1;
  }
}

// ---- K7sr: node-space stats reduce -> statsB[5][128] -----------------------------------
__global__ __launch_bounds__(256) void k7sr(const float* __restrict__ h1h,
        const float* __restrict__ crossrow, const bf16* __restrict__ xa,
        const bf16* __restrict__ xb, const int* __restrict__ cst,
        const int* __restrict__ cdt, float* __restrict__ statsB) {
  int t = threadIdx.x;
  int w = t >> 6, lane = t & 63, k = lane & 15;
  int rg = t >> 4;
  int c0 = k * 8;
  int base = blockIdx.x * 200;
  float A1[8] = {0,0,0,0,0,0,0,0}, A2[8] = {0,0,0,0,0,0,0,0};
  float B1[8] = {0,0,0,0,0,0,0,0}, B2[8] = {0,0,0,0,0,0,0,0};
  float Cc[8] = {0,0,0,0,0,0,0,0};
  for (int r = rg; r < 200; r += 16) {
    int n = base + r;
    f32x4 h0 = *(const f32x4*)(h1h + (size_t)n * F + c0);
    f32x4 h1 = *(const f32x4*)(h1h + (size_t)n * F + c0 + 4);
    f32x4 cr0 = *(const f32x4*)(crossrow + (size_t)n * F + c0);
    f32x4 cr1 = *(const f32x4*)(crossrow + (size_t)n * F + c0 + 4);
    bf16x8 av = *(const bf16x8*)(xa + (size_t)n * F + c0);
    bf16x8 bv = *(const bf16x8*)(xb + (size_t)n * F + c0);
    float ca = (float)cst[n], cb = (float)cdt[n];
#pragma unroll
    for (int j = 0; j < 4; ++j) {
      A1[j] += h0[j]; A2[j] += h0[j] * h0[j];
      A1[j + 4] += h1[j]; A2[j + 4] += h1[j] * h1[j];
      Cc[j] += cr0[j]; Cc[j + 4] += cr1[j];
    }
#pragma unroll
    for (int j = 0; j < 8; ++j) {
      float a = (float)av[j], b = (float)bv[j];
      B1[j] += ca * a + cb * b;
      B2[j] += ca * a * a + cb * b * b;
    }
  }
#pragma unroll
  for (int m = 16; m < 64; m <<= 1) {
#pragma unroll
    for (int j = 0; j < 8; ++j) {
      A1[j] += __shfl_xor(A1[j], m); A2[j] += __shfl_xor(A2[j], m);
      B1[j] += __shfl_xor(B1[j], m); B2[j] += __shfl_xor(B2[j], m);
      Cc[j] += __shfl_xor(Cc[j], m);
    }
  }
  __shared__ float L[4][5][128];
  if (lane < 16) {
#pragma unroll
    for (int j = 0; j < 8; ++j) {
      L[w][0][c0 + j] = A1[j]; L[w][1][c0 + j] = A2[j];
      L[w][2][c0 + j] = B1[j]; L[w][3][c0 + j] = B2[j];
      L[w][4][c0 + j] = Cc[j];
    }
  }
  __syncthreads();
  if (t < 128) {
#pragma unroll
    for (int term = 0; term < 5; ++term) {
      float v = L[0][term][t] + L[1][term][t] + L[2][term][t] + L[3][term][t];
      atomicAdd(&statsB[term * 128 + t], v);
    }
  }
}

// ---- K8: finalize BN affine folds + transpose W2 to bf16 + params4 ---------------------
__global__ __launch_bounds__(256) void k8_final(const float* __restrict__ statsB,
        const float* __restrict__ bn_g, const float* __restrict__ bn_b,
        const float* __restrict__ b1, const float* __restrict__ W2,
        const float* __restrict__ b2, const float* __restrict__ lng,
        const float* __restrict__ lnb, const float* __restrict__ W3,
        float* __restrict__ P, float* __restrict__ Qh, float* __restrict__ Qt,
        u16* __restrict__ W2t, f32x4* __restrict__ params4) {
  int t = threadIdx.x;
  if (t < 128) {
    float A1 = statsB[t], A2 = statsB[128 + t], B1v = statsB[256 + t];
    float B2v = statsB[384 + t], Cv = statsB[512 + t];
    float b1c = b1[t];
    float S = A1 + B1v + (float)TAILN * b1c;
    float Q = A2 + B2v + 2.f * Cv + 2.f * b1c * B1v + (float)TAILN * b1c * b1c;
    float mean = S * (1.0f / NE);
    float var = Q * (1.0f / NE) - mean * mean;
    float rs = rsqrtf(var + EPSN);
    float p = bn_g[t] * rs;
    float sh = bn_b[t] - mean * p;
    P[t] = p; Qh[t] = sh; Qt[t] = p * b1c + sh;
    f32x4 pr = {b2[t], lng[t], lnb[t], W3[t]};
    params4[t] = pr;
  }
  for (int i = 0; i < 64; ++i) {
    int flat = i * 256 + t;
    int k = flat >> 7, c = flat & 127;
    union { bf16 b; u16 u; } cv;
    cv.b = (bf16)W2[(size_t)k * F + c];
    W2t[(size_t)c * F + k] = cv.u;   // W2t[c][k]
  }
}

// ---- K9a: head GEMM g2 = dinv[row] * (relu(P*h1h+Qh) @ W2)  (bf16 MFMA) ----------------
__global__ __launch_bounds__(256) void k9a_headgemm(const float* __restrict__ h1h,
        const float* __restrict__ P, const float* __restrict__ Qh,
        const u16* __restrict__ W2t, const float* __restrict__ dinv,
        bf16* __restrict__ g2) {
  __shared__ __align__(16) bf16 A[64 * 128];
  __shared__ __align__(16) bf16 B[128 * 128];
  int t = threadIdx.x;
  int row0 = blockIdx.x * 64;
  const bf16x8* srcB = (const bf16x8*)W2t;
#pragma unroll
  for (int i = 0; i < 8; ++i) {
    int ch = i * 256 + t;
    int r = ch >> 4, cir = ch & 15;
    *(bf16x8*)&B[r * 128 + ((cir ^ (r & 7)) << 3)] = srcB[ch];
  }
  {
    int r = t >> 2, sub = t & 3;
    int gr = row0 + r;
#pragma unroll
    for (int j = 0; j < 4; ++j) {
      int c0 = sub * 32 + j * 8;
      f32x4 v0 = {0.f,0.f,0.f,0.f}, v1 = {0.f,0.f,0.f,0.f};
      if (gr < NN) {
        v0 = *(const f32x4*)(h1h + (size_t)gr * F + c0);
        v1 = *(const f32x4*)(h1h + (size_t)gr * F + c0 + 4);
      }
      f32x4 p0 = *(const f32x4*)(P + c0), p1 = *(const f32x4*)(P + c0 + 4);
      f32x4 q0 = *(const f32x4*)(Qh + c0), q1 = *(const f32x4*)(Qh + c0 + 4);
      bf16x8 o;
#pragma unroll
      for (int m = 0; m < 4; ++m) {
        o[m]     = (bf16)fmaxf(v0[m] * p0[m] + q0[m], 0.f);
        o[m + 4] = (bf16)fmaxf(v1[m] * p1[m] + q1[m], 0.f);
      }
      int ch = c0 >> 3;
      *(bf16x8*)&A[r * 128 + ((ch ^ (r & 7)) << 3)] = o;
    }
  }
  __syncthreads();
  int lane = t & 63, w = t >> 6;
  int lr = lane & 15, g = lane >> 4;
  int arow = w * 16 + lr;
  bf16x8 af[4];
#pragma unroll
  for (int kk = 0; kk < 4; ++kk)
    af[kk] = *(const bf16x8*)&A[arow * 128 + (((kk * 4 + g) ^ (arow & 7)) << 3)];
  f32x4 acc[8];
#pragma unroll
  for (int n = 0; n < 8; ++n) {
    f32x4 a = {0.f,0.f,0.f,0.f};
    int col = n * 16 + lr;
#pragma unroll
    for (int kk = 0; kk < 4; ++kk) {
      bf16x8 bfr = *(const bf16x8*)&B[col * 128 + (((kk * 4 + g) ^ (col & 7)) << 3)];
      a = __builtin_amdgcn_mfma_f32_16x16x32_bf16(af[kk], bfr, a, 0, 0, 0);
    }
    acc[n] = a;
  }
#pragma unroll
  for (int r4 = 0; r4 < 4; ++r4) {
    int gr = row0 + w * 16 + g * 4 + r4;
    if (gr < NN) {
      float dr = dinv[gr];
#pragma unroll
      for (int n = 0; n < 8; ++n)
        g2[(size_t)gr * F + n * 16 + lr] = (bf16)(acc[n][r4] * dr);
    }
  }
}

// ---- K9b: head conv2 + LN + relu + W3 (gathers pre-scaled g2 rows) ---------------------
__global__ __launch_bounds__(256) void k9b_head(const int* __restrict__ ptr,
        const int* __restrict__ csr_s, const bf16* __restrict__ g2,
        const float* __restrict__ dinv,
        const float* __restrict__ b2, const float* __restrict__ lng,
        const float* __restrict__ lnb, const float* __restrict__ W3,
        const float* __restrict__ b3, float* __restrict__ out) {
  int w = threadIdx.x >> 6, lane = threadIdx.x & 63;
  int g = lane >> 4, k = lane & 15;
  int i = blockIdx.x * 4 + w;
  int c0 = k * 8;
  int beg = ptr[i], end = ptr[i + 1];
  float acc[8] = {0,0,0,0,0,0,0,0};
  int q = beg + g;
  for (; q + 4 < end; q += 8) {
    int s0 = csr_s[q] & 0xFFFF, s1 = csr_s[q + 4] & 0xFFFF;
    bf16x8 h0 = *(const bf16x8*)(g2 + (size_t)s0 * F + c0);
    bf16x8 h1 = *(const bf16x8*)(g2 + (size_t)s1 * F + c0);
#pragma unroll
    for (int j = 0; j < 8; ++j)
      acc[j] += (float)h0[j] + (float)h1[j];
  }
  if (q < end) {
    int s0 = csr_s[q] & 0xFFFF;
    bf16x8 h0 = *(const bf16x8*)(g2 + (size_t)s0 * F + c0);
#pragma unroll
    for (int j = 0; j < 8; ++j) acc[j] += (float)h0[j];
  }
#pragma unroll
  for (int m = 16; m < 64; m <<= 1) {
#pragma unroll
    for (int j = 0; j < 8; ++j) acc[j] += __shfl_xor(acc[j], m);
  }
  float di = dinv[i];
  bf16x8 self = *(const bf16x8*)(g2 + (size_t)i * F + c0);   // = dinv[i]*h2ph[i]
  f32x4 b2A = *(const f32x4*)(b2 + c0), b2B = *(const f32x4*)(b2 + c0 + 4);
  float h2[8];
#pragma unroll
  for (int j = 0; j < 4; ++j) {
    h2[j]     = di * (acc[j]     + (float)self[j])     + b2A[j];
    h2[j + 4] = di * (acc[j + 4] + (float)self[j + 4]) + b2B[j];
  }
  float s1v = 0.f, s2v = 0.f;
#pragma unroll
  for (int j = 0; j < 8; ++j) { s1v += h2[j]; s2v += h2[j] * h2[j]; }
#pragma unroll
  for (int m = 1; m < 16; m <<= 1) { s1v += __shfl_xor(s1v, m); s2v += __shfl_xor(s2v, m); }
  float mean = s1v * (1.0f / F);
  float var = s2v * (1.0f / F) - mean * mean;
  float rs = rsqrtf(var + EPSN);
  f32x4 lgA = *(const f32x4*)(lng + c0), lgB = *(const f32x4*)(lng + c0 + 4);
  f32x4 lbA = *(const f32x4*)(lnb + c0), lbB = *(const f32x4*)(lnb + c0 + 4);
  f32x4 w3A = *(const f32x4*)(W3 + c0),  w3B = *(const f32x4*)(W3 + c0 + 4);
  float y = 0.f;
#pragma unroll
  for (int j = 0; j < 4; ++j) {
    y += fmaxf((h2[j]     - mean) * rs * lgA[j] + lbA[j], 0.f) * w3A[j];
    y += fmaxf((h2[j + 4] - mean) * rs * lgB[j] + lbB[j], 0.f) * w3B[j];
  }
#pragma unroll
  for (int m = 1; m < 16; m <<= 1) y += __shfl_xor(y, m);
  if (lane == 0) out[i] = y + b3[0];
}

// ---- K9c: tail fused (256 edges/block, LDS B) — R9 structure ---------------------------
__global__ __launch_bounds__(256) void k9c_tail(const int* __restrict__ srcb,
        const int* __restrict__ dstb, const bf16* __restrict__ xa,
        const bf16* __restrict__ xb, const float* __restrict__ P,
        const float* __restrict__ Qt, const u16* __restrict__ W2t,
        const f32x4* __restrict__ params4, const float* __restrict__ b3,
        float* __restrict__ out) {
  __shared__ __align__(16) bf16 B[128 * 128];
  int t = threadIdx.x;
  const bf16x8* srcB = (const bf16x8*)W2t;
#pragma unroll
  for (int i = 0; i < 8; ++i) {
    int ch = i * 256 + t;
    int r = ch >> 4, cir = ch & 15;
    *(bf16x8*)&B[r * 128 + ((cir ^ (r & 7)) << 3)] = srcB[ch];
  }
  __syncthreads();
  int lane = t & 63, w = t >> 6;
  int lr = lane & 15, g = lane >> 4;
  int ebase = NN + blockIdx.x * 256 + w * 64;
  float b3v = b3[0];
  for (int rc = 0; rc < 4; ++rc) {
    int e = ebase + rc * 16 + lr;
    bool ok = (e < NE);
    int se = 0, de = 0;
    if (ok) { se = srcb[e]; de = dstb[e]; }
    bf16x8 af[4];
#pragma unroll
    for (int kk = 0; kk < 4; ++kk) {
      int c0 = kk * 32 + g * 8;
      bf16x8 o;
      if (ok) {
        bf16x8 av = *(const bf16x8*)(xa + (size_t)se * F + c0);
        bf16x8 bv = *(const bf16x8*)(xb + (size_t)de * F + c0);
        f32x4 p0 = *(const f32x4*)(P + c0), p1 = *(const f32x4*)(P + c0 + 4);
        f32x4 q0 = *(const f32x4*)(Qt + c0), q1 = *(const f32x4*)(Qt + c0 + 4);
#pragma unroll
        for (int m = 0; m < 4; ++m) {
          o[m]     = (bf16)fmaxf(((float)av[m] + (float)bv[m]) * p0[m] + q0[m], 0.f);
          o[m + 4] = (bf16)fmaxf(((float)av[m + 4] + (float)bv[m + 4]) * p1[m] + q1[m], 0.f);
        }
      } else {
#pragma unroll
        for (int m = 0; m < 8; ++m) o[m] = (bf16)0.f;
      }
      af[kk] = o;
    }
    f32x4 acc[8];
#pragma unroll
    for (int n = 0; n < 8; ++n) {
      f32x4 a = {0.f,0.f,0.f,0.f};
      int col = n * 16 + lr;
#pragma unroll
      for (int kk = 0; kk < 4; ++kk) {
        bf16x8 bfr = *(const bf16x8*)&B[col * 128 + (((kk * 4 + g) ^ (col & 7)) << 3)];
        a = __builtin_amdgcn_mfma_f32_16x16x32_bf16(af[kk], bfr, a, 0, 0, 0);
      }
      acc[n] = a;
    }
#pragma unroll
    for (int r4 = 0; r4 < 4; ++r4) {
      float vv[8];
      float s = 0.f, q = 0.f;
#pragma unroll
      for (int n = 0; n < 8; ++n) {
        float v = acc[n][r4] + params4[n * 16 + lr][0];
        vv[n] = v; s += v; q += v * v;
      }
#pragma unroll
      for (int m = 1; m < 16; m <<= 1) { s += __shfl_xor(s, m); q += __shfl_xor(q, m); }
      float mean = s * (1.0f / F);
      float var = q * (1.0f / F) - mean * mean;
      float rs = rsqrtf(var + EPSN);
      float o = 0.f;
#pragma unroll
      for (int n = 0; n < 8; ++n) {
        f32x4 pr = params4[n * 16 + lr];
        o += fmaxf((vv[n] - mean) * rs * pr[1] + pr[2], 0.f) * pr[3];
      }
#pragma unroll
      for (int m = 1; m < 16; m <<= 1) o += __shfl_xor(o, m);
      int eo = ebase + rc * 16 + g * 4 + r4;
      if (lr == 0 && eo < NE) out[eo] = o + b3v;
    }
  }
}

// ======================================================================================
extern "C" void kernel_launch(void* const* d_in, const int* in_sizes, int n_in,
                              void* d_out, int out_size, void* d_ws, size_t ws_size,
                              hipStream_t stream) {
  const float* x   = (const float*)d_in[0];
  const void*  ei  = d_in[1];
  const float* W1  = (const float*)d_in[2];
  const float* b1  = (const float*)d_in[3];
  const float* bng = (const float*)d_in[4];
  const float* bnb = (const float*)d_in[5];
  const float* W2  = (const float*)d_in[6];
  const float* b2  = (const float*)d_in[7];
  const float* lng = (const float*)d_in[8];
  const float* lnb = (const float*)d_in[9];
  const float* W3  = (const float*)d_in[10];
  const float* b3  = (const float*)d_in[11];
  float* out = (float*)d_out;

  char* ws = (char*)d_ws;
  size_t off = 0;
  auto alloc = [&](size_t bytes) -> char* {
    off = (off + 511) & ~(size_t)511;
    char* p = ws + off;
    off += bytes;
    return p;
  };
  const size_t NFh = (size_t)NN * F * 2;   // bf16 node-row tables
  bf16*  xa     = (bf16*)alloc(NFh);
  bf16*  xb     = (bf16*)alloc(NFh);
  bf16*  hx     = (bf16*)alloc((size_t)NN * 256 * 2);  // interleaved [dinv*hh|xa] rows
  float* h1h    = (float*)alloc((size_t)NN * F * 4);
  float* crossr = (float*)alloc((size_t)NN * F * 4);
  int*   srcb   = (int*)alloc((size_t)NE * 4);
  int*   dstb   = (int*)alloc((size_t)NE * 4);
  int*   csr_s  = (int*)alloc((size_t)NE * 4);
  int*   cnt    = (int*)alloc((size_t)NN * 4);
  int*   cst    = (int*)alloc((size_t)NN * 4);
  int*   cdt    = (int*)alloc((size_t)NN * 4);
  int*   ptrb   = (int*)alloc((size_t)(NN + 1) * 4);
  int*   cursor = (int*)alloc((size_t)NN * 4);
  float* dinv   = (float*)alloc((size_t)NN * 4);
  float* invdeg = (float*)alloc((size_t)NN * 4);
  float* statsB = (float*)alloc(5 * 128 * 4);
  float* Pp     = (float*)alloc(128 * 4);
  float* Qh     = (float*)alloc(128 * 4);
  float* Qt     = (float*)alloc(128 * 4);
  u16*   W2t    = (u16*)alloc((size_t)F * F * 2);
  f32x4* params4= (f32x4*)alloc(128 * 16);
  bf16*  g2     = hx;  // alias: hx dead after k6 (k7sr reads xa/xb/h1h/crossr only)

  hipMemsetAsync(cnt, 0, (size_t)NN * 4, stream);
  hipMemsetAsync(cst, 0, (size_t)NN * 4, stream);
  hipMemsetAsync(cdt, 0, (size_t)NN * 4, stream);
  hipMemsetAsync(statsB, 0, 5 * 128 * 4, stream);

  k_cvt_idx<<<2500, 256, 0, stream>>>(ei, srcb, dstb, cnt, cst, cdt);
  k1_gemm1<<<dim3(313, 4), 256, 0, stream>>>(x, W1, xa, xb);
  k3_scan<<<1, 1024, 0, stream>>>(cnt, ptrb, cursor, dinv, invdeg);
  kB_fused<<<5000, 256, 0, stream>>>(srcb, dstb, xa, xb, dinv, hx, cursor, csr_s);
  k6_conv1cross<<<5000, 256, 0, stream>>>(ptrb, csr_s, hx, xb, dinv, b1, h1h, crossr);
  k7sr<<<100, 256, 0, stream>>>(h1h, crossr, xa, xb, cst, cdt, statsB);
  k8_final<<<1, 256, 0, stream>>>(statsB, bng, bnb, b1, W2, b2, lng, lnb, W3,
                                  Pp, Qh, Qt, W2t, params4);
  k9a_headgemm<<<313, 256, 0, stream>>>(h1h, Pp, Qh, W2t, dinv, g2);
  k9b_head<<<5000, 256, 0, stream>>>(ptrb, csr_s, g2, dinv, b2, lng, lnb, W3, b3, out);
  k9c_tail<<<2422, 256, 0, stream>>>(srcb, dstb, xa, xb, Pp, Qt, W2t, params4,
                                     b3, out);
}